// Round 2
// baseline (566.653 us; speedup 1.0000x reference)
//
#include <hip/hip_runtime.h>

// PosteriorHiddenTreeMarkovModel — MI355X / gfx950
// R2: g-parallel work partition (8 lanes per node, lane=g; 8 c-values in regs),
// c-major plane layout beta/tbeta[c][tree][loc][g] for full wave coalescing,
// 1024-thread blocks (16 waves/CU), rcp instead of div.
// One block per tree (64 blocks). eps overwrites beta in place on down pass.

namespace {

constexpr int kNT    = 64;
constexpr int kNPT   = 3280;   // nodes per tree
constexpr int kNINT  = 1093;   // internal nodes per tree
constexpr int kLeaf0 = 1093;
constexpr int kNLEAF = 2187;
constexpr int kBP    = kNT * kNPT * 8;    // beta plane stride (floats)
constexpr int kTP    = kNT * kNINT * 8;   // tbeta plane stride (floats)

__global__ __launch_bounds__(1024)
void phtmm_kernel(const float* __restrict__ lamA,   // (8,8,3,8)
                  const float* __restrict__ lamB,   // (8,128,8)
                  const float* __restrict__ lamPi,  // (8,3,8)
                  const float* __restrict__ lamSP,  // (3,8)
                  const int*   __restrict__ x,      // (DIM,)
                  float* __restrict__ out,          // (64,8)
                  float* __restrict__ beta,         // 8 planes of kBP
                  float* __restrict__ tbeta)        // 8 planes of kTP
{
    const int t   = blockIdx.x;
    const int tid = threadIdx.x;
    const int OFFS[9] = {0, 1, 4, 13, 40, 121, 364, 1093, 3280};

    __shared__ float sA[1536];   // softmax(A) [i][j][p][g]
    __shared__ float sLA[1536];
    __shared__ float sBm[8192];  // softmax(B over m) [c][m][g]
    __shared__ float sPi[192];   // [c][p][g]
    __shared__ float sLPi[192];
    __shared__ float sSP[24];    // [p][g]
    __shared__ float sLSP[24];
    __shared__ float sred[1024];

    // ---------- softmaxes into LDS ----------
    for (int col = tid; col < 192; col += 1024) {   // A over axis i
        int j = col / 24; int rem = col - j * 24; int p = rem >> 3; int g = rem & 7;
        float v[8]; float mx = -1e30f;
        #pragma unroll
        for (int i = 0; i < 8; ++i) {
            v[i] = lamA[((i * 8 + j) * 3 + p) * 8 + g];
            mx = fmaxf(mx, v[i]);
        }
        float s = 0.f;
        #pragma unroll
        for (int i = 0; i < 8; ++i) { v[i] = expf(v[i] - mx); s += v[i]; }
        float inv = 1.f / s;
        #pragma unroll
        for (int i = 0; i < 8; ++i) {
            int idx = ((i * 8 + j) * 3 + p) * 8 + g;
            float sm = v[i] * inv;
            sA[idx]  = sm;
            sLA[idx] = logf(sm);
        }
    }
    for (int row = tid; row < 64; row += 1024) {    // B over axis m
        int c = row >> 3; int g = row & 7;
        float mx = -1e30f;
        for (int m = 0; m < 128; ++m)
            mx = fmaxf(mx, lamB[(c * 128 + m) * 8 + g]);
        float s = 0.f;
        for (int m = 0; m < 128; ++m)
            s += expf(lamB[(c * 128 + m) * 8 + g] - mx);
        float inv = 1.f / s;
        for (int m = 0; m < 128; ++m) {
            int idx = (c * 128 + m) * 8 + g;
            sBm[idx] = expf(lamB[idx] - mx) * inv;
        }
    }
    for (int col = tid; col < 24; col += 1024) {    // Pi over axis c
        int p = col >> 3; int g = col & 7;
        float v[8]; float mx = -1e30f;
        #pragma unroll
        for (int c = 0; c < 8; ++c) {
            v[c] = lamPi[(c * 3 + p) * 8 + g];
            mx = fmaxf(mx, v[c]);
        }
        float s = 0.f;
        #pragma unroll
        for (int c = 0; c < 8; ++c) { v[c] = expf(v[c] - mx); s += v[c]; }
        float inv = 1.f / s;
        #pragma unroll
        for (int c = 0; c < 8; ++c) {
            int idx = (c * 3 + p) * 8 + g;
            float sm = v[c] * inv;
            sPi[idx]  = sm;
            sLPi[idx] = logf(sm);
        }
    }
    if (tid < 8) {                                   // SP over axis p
        int g = tid;
        float v0 = lamSP[g], v1 = lamSP[8 + g], v2 = lamSP[16 + g];
        float mx = fmaxf(v0, fmaxf(v1, v2));
        float e0 = expf(v0 - mx), e1 = expf(v1 - mx), e2 = expf(v2 - mx);
        float inv = 1.f / (e0 + e1 + e2);
        sSP[g] = e0 * inv; sSP[8 + g] = e1 * inv; sSP[16 + g] = e2 * inv;
        sLSP[g] = logf(e0 * inv); sLSP[8 + g] = logf(e1 * inv); sLSP[16 + g] = logf(e2 * inv);
    }
    __syncthreads();

    const int xbase = t * kNPT;
    const int bbase = t * kNPT * 8;    // offset within a beta plane
    const int tbase = t * kNINT * 8;   // offset within a tbeta plane

    // ---------- up pass: leaves ----------
    for (int u = tid; u < kNLEAF * 8; u += 1024) {
        int g  = u & 7;
        int li = u >> 3;
        int loc = kLeaf0 + li;
        int p   = li % 3;
        int xv  = x[xbase + loc];
        float v[8]; float s = 0.f;
        #pragma unroll
        for (int c = 0; c < 8; ++c) {
            v[c] = sPi[(c * 3 + p) * 8 + g] * sBm[(c * 128 + xv) * 8 + g];
            s += v[c];
        }
        float ig = __builtin_amdgcn_rcpf(s);
        int off = bbase + loc * 8 + g;
        #pragma unroll
        for (int c = 0; c < 8; ++c)
            beta[c * kBP + off] = v[c] * ig;
    }
    __syncthreads();

    // ---------- up pass: internal levels ----------
    for (int d = 7; d >= 1; --d) {
        int pbase  = OFFS[d - 1];
        int pcount = OFFS[d] - OFFS[d - 1];
        int cbase  = OFFS[d];
        for (int u = tid; u < pcount * 8; u += 1024) {
            int g  = u & 7;
            int pi = u >> 3;
            int locp = pbase + pi;
            int c0   = cbase + 3 * pi;
            float acc[8];
            #pragma unroll
            for (int i = 0; i < 8; ++i) acc[i] = 0.f;
            #pragma unroll
            for (int k = 0; k < 3; ++k) {   // child pos == k
                int coff = bbase + (c0 + k) * 8 + g;
                float bj[8];
                #pragma unroll
                for (int j = 0; j < 8; ++j) bj[j] = beta[j * kBP + coff];
                float spg = sSP[k * 8 + g];
                #pragma unroll
                for (int i = 0; i < 8; ++i) {
                    float s = 0.f;
                    #pragma unroll
                    for (int j = 0; j < 8; ++j)
                        s += sA[((i * 8 + j) * 3 + k) * 8 + g] * bj[j];
                    acc[i] += spg * s;
                }
            }
            int toff = tbase + locp * 8 + g;
            #pragma unroll
            for (int i = 0; i < 8; ++i) tbeta[i * kTP + toff] = acc[i];
            int xv = x[xbase + locp];
            float s = 0.f;
            #pragma unroll
            for (int i = 0; i < 8; ++i) {
                acc[i] *= sBm[(i * 128 + xv) * 8 + g];
                s += acc[i];
            }
            float ig = __builtin_amdgcn_rcpf(s);
            int boff = bbase + locp * 8 + g;
            #pragma unroll
            for (int i = 0; i < 8; ++i) beta[i * kBP + boff] = acc[i] * ig;
        }
        __syncthreads();
    }

    // ---------- down pass ----------
    float ell = 0.f;                   // this thread's g = tid & 7 partial

    if (tid < 8) {                     // root: eps == beta (in place); Bm term
        int g  = tid;
        int xv = x[xbase];
        int off = bbase + g;           // loc = 0
        #pragma unroll
        for (int c = 0; c < 8; ++c)
            ell += beta[c * kBP + off] * sBm[(c * 128 + xv) * 8 + g];
    }

    for (int d = 1; d <= 7; ++d) {
        int cbase  = OFFS[d];
        int ccount = OFFS[d + 1] - OFFS[d];
        int pbase  = OFFS[d - 1];
        for (int u = tid; u < ccount * 8; u += 1024) {
            int g  = u & 7;
            int ci = u >> 3;
            int locc = cbase + ci;
            int p    = ci % 3;
            int locp = pbase + ci / 3;
            int poff = bbase + locp * 8 + g;
            int toff = tbase + locp * 8 + g;
            float r[8];
            #pragma unroll
            for (int i = 0; i < 8; ++i)
                r[i] = beta[i * kBP + poff] * __builtin_amdgcn_rcpf(tbeta[i * kTP + toff]);
            int coff = bbase + locc * 8 + g;
            float bj[8];
            #pragma unroll
            for (int j = 0; j < 8; ++j) bj[j] = beta[j * kBP + coff];
            float spg = sSP[p * 8 + g];
            float esum = 0.f, lg = 0.f;
            float ev[8];
            #pragma unroll
            for (int j = 0; j < 8; ++j) {
                float s1 = 0.f, s2 = 0.f;
                #pragma unroll
                for (int i = 0; i < 8; ++i) {
                    int ai = ((i * 8 + j) * 3 + p) * 8 + g;
                    float ra = r[i] * sA[ai];
                    s1 += ra;
                    s2 += ra * sLA[ai];
                }
                float base = spg * bj[j];
                ev[j] = base * s1;
                lg   += base * s2;
                esum += ev[j];
            }
            lg += esum * sLSP[p * 8 + g];
            #pragma unroll
            for (int j = 0; j < 8; ++j) beta[j * kBP + coff] = ev[j];  // eps in place
            int xv = x[xbase + locc];
            #pragma unroll
            for (int c = 0; c < 8; ++c)
                lg += ev[c] * sBm[(c * 128 + xv) * 8 + g];
            if (locc >= kLeaf0) {
                #pragma unroll
                for (int c = 0; c < 8; ++c)
                    lg += ev[c] * sLPi[(c * 3 + p) * 8 + g];
            }
            ell += lg;
        }
        __syncthreads();
    }

    // ---------- block reduction (g classes preserved: strides are multiples of 8) ----------
    sred[tid] = ell;
    __syncthreads();
    for (int s = 512; s >= 8; s >>= 1) {
        if (tid < s) sred[tid] += sred[tid + s];
        __syncthreads();
    }
    if (tid < 8) out[t * 8 + tid] = -sred[tid];
}

} // namespace

extern "C" void kernel_launch(void* const* d_in, const int* in_sizes, int n_in,
                              void* d_out, int out_size, void* d_ws, size_t ws_size,
                              hipStream_t stream) {
    const float* lamA  = (const float*)d_in[0];
    const float* lamB  = (const float*)d_in[1];
    const float* lamPi = (const float*)d_in[2];
    const float* lamSP = (const float*)d_in[3];
    const int*   x     = (const int*)d_in[4];
    // pos/leaves/batch derived analytically; unused.
    float* out   = (float*)d_out;
    float* beta  = (float*)d_ws;                        // 8 * kBP floats
    float* tbeta = beta + (size_t)8 * kBP;              // 8 * kTP floats
    phtmm_kernel<<<dim3(kNT), dim3(1024), 0, stream>>>(
        lamA, lamB, lamPi, lamSP, x, out, beta, tbeta);
}

// Round 3
// 218.483 us; speedup vs baseline: 2.5936x; 2.5936x over previous
//
#include <hip/hip_runtime.h>

// PosteriorHiddenTreeMarkovModel — MI355X / gfx950
// R3: subtree decomposition. Tree split at level 3 (27 subtrees/tree, each a
// depth-4 subtree of 121 nodes whose beta/tbeta fit in LDS).
//   k0: softmaxes -> ws params
//   k1 (1728 blocks): subtree up-pass in LDS, writes only root beta (b3)
//   k2 (64 blocks): levels 0-3 up+down, writes out partials + eps level-3 (e3)
//   k3 (1728 blocks): replays subtree up-pass in LDS (recompute ~free), then
//       down-pass in LDS; ell accumulated in regs, atomicAdd into out.
// Levels 4-7 beta/tbeta never touch global: ~5-10 MB total HBM traffic.
// LDS node stride 68 floats (4 mod 32 banks) -> <=2-way conflicts (free).

namespace {

constexpr int kNPT = 3280;
// Global level offsets: OFF[d] = (3^d-1)/2; level d occupies [OFF[d], OFF[d+1])
// Subtree-local levels e=0..4 <-> global levels 3..7.
__device__ __constant__ int LO[6]  = {0, 1, 4, 13, 40, 121};      // local offsets
__device__ __constant__ int P3[5]  = {1, 3, 9, 27, 81};           // 3^e
__device__ __constant__ int GO[5]  = {13, 40, 121, 364, 1093};    // OFF[3+e]

// ws param layout (floats)
constexpr int oA   = 0;      // 1536 softmax(A)   [i][j][p][g]
constexpr int oLA  = 1536;   // 1536 log
constexpr int oBm  = 3072;   // 8192 softmax(B|m) [c][m][g]
constexpr int oPi  = 11264;  // 192  softmax(Pi|c)[c][p][g]
constexpr int oLPi = 11456;  // 192
constexpr int oSP  = 11648;  // 24   softmax(SP|p)[p][g]
constexpr int oLSP = 11672;  // 24
constexpr int oEnd = 11712;
constexpr int kB3  = 64 * 27 * 64;   // b3 / e3 element counts

__global__ __launch_bounds__(256)
void k0_params(const float* __restrict__ lamA, const float* __restrict__ lamB,
               const float* __restrict__ lamPi, const float* __restrict__ lamSP,
               float* __restrict__ P)
{
    const int tid = threadIdx.x;
    for (int col = tid; col < 192; col += 256) {          // A over axis i
        int j = col / 24; int rem = col - j * 24; int p = rem >> 3; int g = rem & 7;
        float v[8]; float mx = -1e30f;
        #pragma unroll
        for (int i = 0; i < 8; ++i) {
            v[i] = lamA[((i * 8 + j) * 3 + p) * 8 + g];
            mx = fmaxf(mx, v[i]);
        }
        float s = 0.f;
        #pragma unroll
        for (int i = 0; i < 8; ++i) { v[i] = expf(v[i] - mx); s += v[i]; }
        float inv = 1.f / s;
        #pragma unroll
        for (int i = 0; i < 8; ++i) {
            int idx = ((i * 8 + j) * 3 + p) * 8 + g;
            float sm = v[i] * inv;
            P[oA + idx]  = sm;
            P[oLA + idx] = logf(sm);
        }
    }
    for (int row = tid; row < 64; row += 256) {           // B over axis m
        int c = row >> 3; int g = row & 7;
        float mx = -1e30f;
        for (int m = 0; m < 128; ++m)
            mx = fmaxf(mx, lamB[(c * 128 + m) * 8 + g]);
        float s = 0.f;
        for (int m = 0; m < 128; ++m)
            s += expf(lamB[(c * 128 + m) * 8 + g] - mx);
        float inv = 1.f / s;
        for (int m = 0; m < 128; ++m) {
            int idx = (c * 128 + m) * 8 + g;
            P[oBm + idx] = expf(lamB[idx] - mx) * inv;
        }
    }
    for (int col = tid; col < 24; col += 256) {           // Pi over axis c
        int p = col >> 3; int g = col & 7;
        float v[8]; float mx = -1e30f;
        #pragma unroll
        for (int c = 0; c < 8; ++c) {
            v[c] = lamPi[(c * 3 + p) * 8 + g];
            mx = fmaxf(mx, v[c]);
        }
        float s = 0.f;
        #pragma unroll
        for (int c = 0; c < 8; ++c) { v[c] = expf(v[c] - mx); s += v[c]; }
        float inv = 1.f / s;
        #pragma unroll
        for (int c = 0; c < 8; ++c) {
            int idx = (c * 3 + p) * 8 + g;
            float sm = v[c] * inv;
            P[oPi + idx]  = sm;
            P[oLPi + idx] = logf(sm);
        }
    }
    if (tid < 8) {                                        // SP over axis p
        int g = tid;
        float v0 = lamSP[g], v1 = lamSP[8 + g], v2 = lamSP[16 + g];
        float mx = fmaxf(v0, fmaxf(v1, v2));
        float e0 = expf(v0 - mx), e1 = expf(v1 - mx), e2 = expf(v2 - mx);
        float inv = 1.f / (e0 + e1 + e2);
        P[oSP + g]       = e0 * inv; P[oSP + 8 + g]  = e1 * inv; P[oSP + 16 + g] = e2 * inv;
        P[oLSP + g]      = logf(e0 * inv);
        P[oLSP + 8 + g]  = logf(e1 * inv);
        P[oLSP + 16 + g] = logf(e2 * inv);
    }
}

// ---------------- k1: subtree up-pass, emit root beta ----------------
__global__ __launch_bounds__(256)
void k1_up(const float* __restrict__ P, const int* __restrict__ x,
           float* __restrict__ b3)
{
    const int blk = blockIdx.x, t = blk / 27, q = blk % 27, tid = threadIdx.x;
    __shared__ float sA[1536], sPi[192], sSP[24];
    __shared__ float bL[121 * 68];
    for (int i = tid; i < 1536; i += 256) sA[i] = P[oA + i];
    for (int i = tid; i < 192; i += 256)  sPi[i] = P[oPi + i];
    if (tid < 24) sSP[tid] = P[oSP + tid];
    __syncthreads();
    const float* pBm = P + oBm;
    const int xb = t * kNPT;

    // leaves (local level 4)
    for (int u = tid; u < 81 * 8; u += 256) {
        int g = u & 7, li = u >> 3, p = li % 3;
        int xv = x[xb + 1093 + q * 81 + li];
        float v[8], s = 0.f;
        #pragma unroll
        for (int c = 0; c < 8; ++c) {
            v[c] = sPi[(c * 3 + p) * 8 + g] * pBm[(c * 128 + xv) * 8 + g];
            s += v[c];
        }
        float ig = __builtin_amdgcn_rcpf(s);
        int bo = (40 + li) * 68 + g;
        #pragma unroll
        for (int c = 0; c < 8; ++c) bL[bo + c * 8] = v[c] * ig;
    }
    __syncthreads();

    for (int e = 3; e >= 0; --e) {
        int pcnt = P3[e];
        for (int u = tid; u < pcnt * 8; u += 256) {
            int g = u & 7, pi = u >> 3;
            float acc[8];
            #pragma unroll
            for (int i = 0; i < 8; ++i) acc[i] = 0.f;
            #pragma unroll
            for (int k = 0; k < 3; ++k) {
                int co = (LO[e + 1] + 3 * pi + k) * 68 + g;
                float bj[8];
                #pragma unroll
                for (int j = 0; j < 8; ++j) bj[j] = bL[co + j * 8];
                float spg = sSP[k * 8 + g];
                #pragma unroll
                for (int i = 0; i < 8; ++i) {
                    float s = 0.f;
                    #pragma unroll
                    for (int j = 0; j < 8; ++j)
                        s += sA[((i * 8 + j) * 3 + k) * 8 + g] * bj[j];
                    acc[i] += spg * s;
                }
            }
            int xv = x[xb + GO[e] + q * pcnt + pi];
            float s = 0.f;
            #pragma unroll
            for (int i = 0; i < 8; ++i) {
                acc[i] *= pBm[(i * 128 + xv) * 8 + g];
                s += acc[i];
            }
            float ig = __builtin_amdgcn_rcpf(s);
            if (e == 0) {
                #pragma unroll
                for (int i = 0; i < 8; ++i)
                    b3[(t * 27 + q) * 64 + i * 8 + g] = acc[i] * ig;
            } else {
                int bo = (LO[e] + pi) * 68 + g;
                #pragma unroll
                for (int i = 0; i < 8; ++i) bL[bo + i * 8] = acc[i] * ig;
            }
        }
        __syncthreads();
    }
}

// ---------------- k2: levels 0-3 up+down (one block per tree) ----------------
__global__ __launch_bounds__(256)
void k2_mid(const float* __restrict__ P, const int* __restrict__ x,
            const float* __restrict__ b3, float* __restrict__ e3,
            float* __restrict__ out)
{
    const int t = blockIdx.x, tid = threadIdx.x;
    __shared__ float sA[1536], sLA[1536], sSP[24], sLSP[24];
    __shared__ float bM[13 * 68], tbM[13 * 68], b3L[27 * 68], red[256];
    for (int i = tid; i < 1536; i += 256) { sA[i] = P[oA + i]; sLA[i] = P[oLA + i]; }
    if (tid < 24) { sSP[tid] = P[oSP + tid]; sLSP[tid] = P[oLSP + tid]; }
    for (int u = tid; u < 27 * 64; u += 256) {
        int qq = u >> 6, idx = u & 63;
        b3L[qq * 68 + idx] = b3[(t * 27 + qq) * 64 + idx];
    }
    __syncthreads();
    const float* pBm = P + oBm;
    const int xb = t * kNPT;

    // up: parents at global levels 2,1,0
    for (int f = 2; f >= 0; --f) {
        int pcnt = (f == 2) ? 9 : (f == 1 ? 3 : 1);
        int pl0  = (f == 2) ? 4 : (f == 1 ? 1 : 0);
        int cl0  = (f == 2) ? 13 : (f == 1 ? 4 : 1);
        for (int u = tid; u < pcnt * 8; u += 256) {
            int g = u & 7, pi = u >> 3;
            float acc[8];
            #pragma unroll
            for (int i = 0; i < 8; ++i) acc[i] = 0.f;
            #pragma unroll
            for (int k = 0; k < 3; ++k) {
                float bj[8];
                if (f == 2) {
                    int co = (3 * pi + k) * 68 + g;
                    #pragma unroll
                    for (int j = 0; j < 8; ++j) bj[j] = b3L[co + j * 8];
                } else {
                    int co = (cl0 + 3 * pi + k) * 68 + g;
                    #pragma unroll
                    for (int j = 0; j < 8; ++j) bj[j] = bM[co + j * 8];
                }
                float spg = sSP[k * 8 + g];
                #pragma unroll
                for (int i = 0; i < 8; ++i) {
                    float s = 0.f;
                    #pragma unroll
                    for (int j = 0; j < 8; ++j)
                        s += sA[((i * 8 + j) * 3 + k) * 8 + g] * bj[j];
                    acc[i] += spg * s;
                }
            }
            int ps = (pl0 + pi) * 68 + g;
            #pragma unroll
            for (int i = 0; i < 8; ++i) tbM[ps + i * 8] = acc[i];
            int xv = x[xb + pl0 + pi];
            float s = 0.f;
            #pragma unroll
            for (int i = 0; i < 8; ++i) {
                acc[i] *= pBm[(i * 128 + xv) * 8 + g];
                s += acc[i];
            }
            float ig = __builtin_amdgcn_rcpf(s);
            #pragma unroll
            for (int i = 0; i < 8; ++i) bM[ps + i * 8] = acc[i] * ig;
        }
        __syncthreads();
    }

    float ell = 0.f;
    if (tid < 8) {                        // root Bm term (eps[root]=beta[root])
        int g = tid, xv = x[xb];
        #pragma unroll
        for (int c = 0; c < 8; ++c)
            ell += bM[c * 8 + g] * pBm[(c * 128 + xv) * 8 + g];
    }

    // down: children at global levels 1,2,3
    for (int f = 1; f <= 3; ++f) {
        int ccnt = (f == 1) ? 3 : (f == 2 ? 9 : 27);
        int cl0  = (f == 1) ? 1 : (f == 2 ? 4 : 13);
        int pl0  = (f == 1) ? 0 : (f == 2 ? 1 : 4);
        for (int u = tid; u < ccnt * 8; u += 256) {
            int g = u & 7, ci = u >> 3;
            int p = ci % 3;
            int ps = (pl0 + ci / 3) * 68 + g;
            float r[8];
            #pragma unroll
            for (int i = 0; i < 8; ++i)
                r[i] = bM[ps + i * 8] * __builtin_amdgcn_rcpf(tbM[ps + i * 8]);
            float bj[8];
            if (f == 3) {
                int co = ci * 68 + g;
                #pragma unroll
                for (int j = 0; j < 8; ++j) bj[j] = b3L[co + j * 8];
            } else {
                int co = (cl0 + ci) * 68 + g;
                #pragma unroll
                for (int j = 0; j < 8; ++j) bj[j] = bM[co + j * 8];
            }
            float spg = sSP[p * 8 + g];
            float esum = 0.f, lg = 0.f;
            float ev[8];
            #pragma unroll
            for (int j = 0; j < 8; ++j) {
                float s1 = 0.f, s2 = 0.f;
                #pragma unroll
                for (int i = 0; i < 8; ++i) {
                    int ai = ((i * 8 + j) * 3 + p) * 8 + g;
                    float ra = r[i] * sA[ai];
                    s1 += ra;
                    s2 += ra * sLA[ai];
                }
                float base = spg * bj[j];
                ev[j] = base * s1;
                lg   += base * s2;
                esum += ev[j];
            }
            lg += esum * sLSP[p * 8 + g];
            if (f == 3) {
                #pragma unroll
                for (int j = 0; j < 8; ++j)
                    e3[(t * 27 + ci) * 64 + j * 8 + g] = ev[j];
            } else {
                int co = (cl0 + ci) * 68 + g;
                #pragma unroll
                for (int j = 0; j < 8; ++j) bM[co + j * 8] = ev[j];
            }
            int xv = x[xb + cl0 + ci];
            #pragma unroll
            for (int c = 0; c < 8; ++c)
                lg += ev[c] * pBm[(c * 128 + xv) * 8 + g];
            ell += lg;
        }
        __syncthreads();
    }

    red[tid] = ell;
    __syncthreads();
    for (int s = 128; s >= 8; s >>= 1) {
        if (tid < s) red[tid] += red[tid + s];
        __syncthreads();
    }
    if (tid < 8) out[t * 8 + tid] = -red[tid];
}

// ---------------- k3: subtree up replay + down-pass ----------------
__global__ __launch_bounds__(256)
void k3_down(const float* __restrict__ P, const int* __restrict__ x,
             const float* __restrict__ e3, float* __restrict__ out)
{
    const int blk = blockIdx.x, t = blk / 27, q = blk % 27, tid = threadIdx.x;
    __shared__ float sA[1536], sLA[1536], sPi[192], sLPi[192], sSP[24], sLSP[24];
    __shared__ float bL[121 * 68], tbL[40 * 68], red[256];
    for (int i = tid; i < 1536; i += 256) { sA[i] = P[oA + i]; sLA[i] = P[oLA + i]; }
    for (int i = tid; i < 192; i += 256)  { sPi[i] = P[oPi + i]; sLPi[i] = P[oLPi + i]; }
    if (tid < 24) { sSP[tid] = P[oSP + tid]; sLSP[tid] = P[oLSP + tid]; }
    __syncthreads();
    const float* pBm = P + oBm;
    const int xb = t * kNPT;

    // ---- up replay (same as k1; also store tbeta) ----
    for (int u = tid; u < 81 * 8; u += 256) {
        int g = u & 7, li = u >> 3, p = li % 3;
        int xv = x[xb + 1093 + q * 81 + li];
        float v[8], s = 0.f;
        #pragma unroll
        for (int c = 0; c < 8; ++c) {
            v[c] = sPi[(c * 3 + p) * 8 + g] * pBm[(c * 128 + xv) * 8 + g];
            s += v[c];
        }
        float ig = __builtin_amdgcn_rcpf(s);
        int bo = (40 + li) * 68 + g;
        #pragma unroll
        for (int c = 0; c < 8; ++c) bL[bo + c * 8] = v[c] * ig;
    }
    __syncthreads();

    for (int e = 3; e >= 0; --e) {
        int pcnt = P3[e];
        for (int u = tid; u < pcnt * 8; u += 256) {
            int g = u & 7, pi = u >> 3;
            float acc[8];
            #pragma unroll
            for (int i = 0; i < 8; ++i) acc[i] = 0.f;
            #pragma unroll
            for (int k = 0; k < 3; ++k) {
                int co = (LO[e + 1] + 3 * pi + k) * 68 + g;
                float bj[8];
                #pragma unroll
                for (int j = 0; j < 8; ++j) bj[j] = bL[co + j * 8];
                float spg = sSP[k * 8 + g];
                #pragma unroll
                for (int i = 0; i < 8; ++i) {
                    float s = 0.f;
                    #pragma unroll
                    for (int j = 0; j < 8; ++j)
                        s += sA[((i * 8 + j) * 3 + k) * 8 + g] * bj[j];
                    acc[i] += spg * s;
                }
            }
            int ps = (LO[e] + pi) * 68 + g;
            #pragma unroll
            for (int i = 0; i < 8; ++i) tbL[ps + i * 8] = acc[i];
            if (e > 0) {
                int xv = x[xb + GO[e] + q * pcnt + pi];
                float s = 0.f;
                #pragma unroll
                for (int i = 0; i < 8; ++i) {
                    acc[i] *= pBm[(i * 128 + xv) * 8 + g];
                    s += acc[i];
                }
                float ig = __builtin_amdgcn_rcpf(s);
                #pragma unroll
                for (int i = 0; i < 8; ++i) bL[ps + i * 8] = acc[i] * ig;
            }
        }
        __syncthreads();
    }

    // eps[subtree root] from k2
    if (tid < 64) bL[tid] = e3[(t * 27 + q) * 64 + tid];
    __syncthreads();

    // ---- down pass, local levels 1..4 (global 4..7) ----
    float ell = 0.f;
    for (int e = 1; e <= 4; ++e) {
        int ccnt = P3[e];
        int cl0 = LO[e], pl0 = LO[e - 1];
        for (int u = tid; u < ccnt * 8; u += 256) {
            int g = u & 7, ci = u >> 3;
            int p = ci % 3;
            int ps = (pl0 + ci / 3) * 68 + g;
            float r[8];
            #pragma unroll
            for (int i = 0; i < 8; ++i)
                r[i] = bL[ps + i * 8] * __builtin_amdgcn_rcpf(tbL[ps + i * 8]);
            int co = (cl0 + ci) * 68 + g;
            float bj[8];
            #pragma unroll
            for (int j = 0; j < 8; ++j) bj[j] = bL[co + j * 8];
            float spg = sSP[p * 8 + g];
            float esum = 0.f, lg = 0.f;
            float ev[8];
            #pragma unroll
            for (int j = 0; j < 8; ++j) {
                float s1 = 0.f, s2 = 0.f;
                #pragma unroll
                for (int i = 0; i < 8; ++i) {
                    int ai = ((i * 8 + j) * 3 + p) * 8 + g;
                    float ra = r[i] * sA[ai];
                    s1 += ra;
                    s2 += ra * sLA[ai];
                }
                float base = spg * bj[j];
                ev[j] = base * s1;
                lg   += base * s2;
                esum += ev[j];
            }
            lg += esum * sLSP[p * 8 + g];
            #pragma unroll
            for (int j = 0; j < 8; ++j) bL[co + j * 8] = ev[j];
            int xv = x[xb + GO[e] + q * ccnt + ci];
            #pragma unroll
            for (int c = 0; c < 8; ++c)
                lg += ev[c] * pBm[(c * 128 + xv) * 8 + g];
            if (e == 4) {
                #pragma unroll
                for (int c = 0; c < 8; ++c)
                    lg += ev[c] * sLPi[(c * 3 + p) * 8 + g];
            }
            ell += lg;
        }
        __syncthreads();
    }

    red[tid] = ell;
    __syncthreads();
    for (int s = 128; s >= 8; s >>= 1) {
        if (tid < s) red[tid] += red[tid + s];
        __syncthreads();
    }
    if (tid < 8) atomicAdd(&out[t * 8 + tid], -red[tid]);
}

} // namespace

extern "C" void kernel_launch(void* const* d_in, const int* in_sizes, int n_in,
                              void* d_out, int out_size, void* d_ws, size_t ws_size,
                              hipStream_t stream) {
    const float* lamA  = (const float*)d_in[0];
    const float* lamB  = (const float*)d_in[1];
    const float* lamPi = (const float*)d_in[2];
    const float* lamSP = (const float*)d_in[3];
    const int*   x     = (const int*)d_in[4];
    float* out = (float*)d_out;
    float* P   = (float*)d_ws;          // oEnd floats
    float* b3  = P + oEnd;              // kB3 floats
    float* e3  = b3 + kB3;              // kB3 floats

    k0_params<<<dim3(1),    dim3(256), 0, stream>>>(lamA, lamB, lamPi, lamSP, P);
    k1_up    <<<dim3(1728), dim3(256), 0, stream>>>(P, x, b3);
    k2_mid   <<<dim3(64),   dim3(256), 0, stream>>>(P, x, b3, e3, out);
    k3_down  <<<dim3(1728), dim3(256), 0, stream>>>(P, x, e3, out);
}

// Round 4
// 187.122 us; speedup vs baseline: 3.0283x; 1.1676x over previous
//
#include <hip/hip_runtime.h>

// PosteriorHiddenTreeMarkovModel — MI355X / gfx950
// R4: subtree decomposition (split at level 3) + LDS diet.
//  - tbL eliminated: store per-node pre-norm sum s; beta slots become r=eps/tb
//    in place during the down pass (tb_j = beta_j*s/Bm_j reconstructed on the fly).
//  - k0 precomputes A*logA (sALA) -> down-pass inner loop is 2 FMAs.
//  - node stride 72 (8 banks) -> max 2-way LDS conflicts (free).
//  - k1 uses a level-reuse slot map (108 slots) to stay at 4 blocks/CU.
//  - k3: 49.1 KB LDS -> 3 blocks/CU. Wave-shuffle reductions.

namespace {

constexpr int kNPT = 3280;
constexpr int kST  = 72;              // node record stride (floats)
__device__ __constant__ int LO[6] = {0, 1, 4, 13, 40, 121};   // local level offsets
__device__ __constant__ int P3[5] = {1, 3, 9, 27, 81};        // 3^e
__device__ __constant__ int GO[5] = {13, 40, 121, 364, 1093}; // OFF[3+e]

// ws param layout (floats)
constexpr int oA   = 0;      // 1536 softmax(A)        [i][j][p][g]
constexpr int oALA = 1536;   // 1536 A * log(A)
constexpr int oBm  = 3072;   // 8192 softmax(B|m)      [c][m][g]
constexpr int oPi  = 11264;  // 192  softmax(Pi|c)     [c][p][g]
constexpr int oLPi = 11456;  // 192  log
constexpr int oSP  = 11648;  // 24   softmax(SP|p)     [p][g]
constexpr int oLSP = 11672;  // 24   log
constexpr int oEnd = 11712;
constexpr int kB3  = 64 * 27 * 64;

__global__ __launch_bounds__(256)
void k0_params(const float* __restrict__ lamA, const float* __restrict__ lamB,
               const float* __restrict__ lamPi, const float* __restrict__ lamSP,
               float* __restrict__ P)
{
    const int tid = threadIdx.x;
    __shared__ float rmax[256], rsum[256];

    for (int col = tid; col < 192; col += 256) {          // A over axis i (+ALA)
        int j = col / 24; int rem = col - j * 24; int p = rem >> 3; int g = rem & 7;
        float v[8]; float mx = -1e30f;
        #pragma unroll
        for (int i = 0; i < 8; ++i) {
            v[i] = lamA[((i * 8 + j) * 3 + p) * 8 + g];
            mx = fmaxf(mx, v[i]);
        }
        float s = 0.f;
        #pragma unroll
        for (int i = 0; i < 8; ++i) { v[i] = expf(v[i] - mx); s += v[i]; }
        float inv = 1.f / s;
        #pragma unroll
        for (int i = 0; i < 8; ++i) {
            int idx = ((i * 8 + j) * 3 + p) * 8 + g;
            float sm = v[i] * inv;
            P[oA + idx]   = sm;
            P[oALA + idx] = sm * logf(sm);
        }
    }
    // Bm softmax over m=128: 64 rows x 4 parts of 32
    {
        int row = tid >> 2, part = tid & 3;
        int c = row >> 3, g = row & 7, m0 = part * 32;
        float mx = -1e30f;
        for (int mm = 0; mm < 32; ++mm)
            mx = fmaxf(mx, lamB[(c * 128 + m0 + mm) * 8 + g]);
        rmax[tid] = mx;
        __syncthreads();
        float m4 = fmaxf(fmaxf(rmax[row * 4], rmax[row * 4 + 1]),
                         fmaxf(rmax[row * 4 + 2], rmax[row * 4 + 3]));
        float s = 0.f;
        for (int mm = 0; mm < 32; ++mm)
            s += expf(lamB[(c * 128 + m0 + mm) * 8 + g] - m4);
        rsum[tid] = s;
        __syncthreads();
        float stot = rsum[row * 4] + rsum[row * 4 + 1] + rsum[row * 4 + 2] + rsum[row * 4 + 3];
        float inv = 1.f / stot;
        for (int mm = 0; mm < 32; ++mm) {
            int idx = (c * 128 + m0 + mm) * 8 + g;
            P[oBm + idx] = expf(lamB[idx] - m4) * inv;
        }
    }
    for (int col = tid; col < 24; col += 256) {           // Pi over axis c
        int p = col >> 3; int g = col & 7;
        float v[8]; float mx = -1e30f;
        #pragma unroll
        for (int c = 0; c < 8; ++c) {
            v[c] = lamPi[(c * 3 + p) * 8 + g];
            mx = fmaxf(mx, v[c]);
        }
        float s = 0.f;
        #pragma unroll
        for (int c = 0; c < 8; ++c) { v[c] = expf(v[c] - mx); s += v[c]; }
        float inv = 1.f / s;
        #pragma unroll
        for (int c = 0; c < 8; ++c) {
            int idx = (c * 3 + p) * 8 + g;
            float sm = v[c] * inv;
            P[oPi + idx]  = sm;
            P[oLPi + idx] = logf(sm);
        }
    }
    if (tid < 8) {                                        // SP over axis p
        int g = tid;
        float v0 = lamSP[g], v1 = lamSP[8 + g], v2 = lamSP[16 + g];
        float mx = fmaxf(v0, fmaxf(v1, v2));
        float e0 = expf(v0 - mx), e1 = expf(v1 - mx), e2 = expf(v2 - mx);
        float inv = 1.f / (e0 + e1 + e2);
        P[oSP + g]       = e0 * inv; P[oSP + 8 + g]  = e1 * inv; P[oSP + 16 + g] = e2 * inv;
        P[oLSP + g]      = logf(e0 * inv);
        P[oLSP + 8 + g]  = logf(e1 * inv);
        P[oLSP + 16 + g] = logf(e2 * inv);
    }
}

// ---------------- k1: subtree up-pass, emit root beta (slot-reuse map) -------
__global__ __launch_bounds__(256)
void k1_up(const float* __restrict__ P, const int* __restrict__ x,
           float* __restrict__ b3)
{
    const int blk = blockIdx.x, t = blk / 27, q = blk % 27, tid = threadIdx.x;
    __shared__ float sA[1536], sPi[192], sSP[24];
    __shared__ float bL[108 * kST];
    for (int i = tid; i < 1536; i += 256) sA[i] = P[oA + i];
    for (int i = tid; i < 192; i += 256)  sPi[i] = P[oPi + i];
    if (tid < 24) sSP[tid] = P[oSP + tid];
    __syncthreads();
    const float* pBm = P + oBm;
    const int xb = t * kNPT;
    // slot bases: child level of parent-level e / parent slots
    const int CB[4] = {9, 0, 81, 0};
    const int PB[4] = {0, 9, 0, 81};

    // leaves (local level 4) -> slots 0..80
    for (int u = tid; u < 81 * 8; u += 256) {
        int g = u & 7, li = u >> 3, p = li % 3;
        int xv = x[xb + 1093 + q * 81 + li];
        float v[8], s = 0.f;
        #pragma unroll
        for (int c = 0; c < 8; ++c) {
            v[c] = sPi[(c * 3 + p) * 8 + g] * pBm[(c * 128 + xv) * 8 + g];
            s += v[c];
        }
        float ig = __builtin_amdgcn_rcpf(s);
        int bo = li * kST + g;
        #pragma unroll
        for (int c = 0; c < 8; ++c) bL[bo + c * 8] = v[c] * ig;
    }
    __syncthreads();

    for (int e = 3; e >= 0; --e) {
        int pcnt = P3[e];
        for (int u = tid; u < pcnt * 8; u += 256) {
            int g = u & 7, pi = u >> 3;
            float acc[8];
            #pragma unroll
            for (int i = 0; i < 8; ++i) acc[i] = 0.f;
            #pragma unroll
            for (int k = 0; k < 3; ++k) {
                int co = (CB[e] + 3 * pi + k) * kST + g;
                float bj[8];
                #pragma unroll
                for (int j = 0; j < 8; ++j) bj[j] = bL[co + j * 8];
                float spg = sSP[k * 8 + g];
                #pragma unroll
                for (int i = 0; i < 8; ++i) {
                    float s = 0.f;
                    #pragma unroll
                    for (int j = 0; j < 8; ++j)
                        s += sA[((i * 8 + j) * 3 + k) * 8 + g] * bj[j];
                    acc[i] += spg * s;
                }
            }
            int xv = x[xb + GO[e] + q * pcnt + pi];
            float s = 0.f;
            #pragma unroll
            for (int i = 0; i < 8; ++i) {
                acc[i] *= pBm[(i * 128 + xv) * 8 + g];
                s += acc[i];
            }
            float ig = __builtin_amdgcn_rcpf(s);
            if (e == 0) {
                #pragma unroll
                for (int i = 0; i < 8; ++i)
                    b3[(t * 27 + q) * 64 + i * 8 + g] = acc[i] * ig;
            } else {
                int bo = (PB[e] + pi) * kST + g;
                #pragma unroll
                for (int i = 0; i < 8; ++i) bL[bo + i * 8] = acc[i] * ig;
            }
        }
        __syncthreads();
    }
}

// ---------------- k2: levels 0-3 up+down (one block per tree) ----------------
__global__ __launch_bounds__(256)
void k2_mid(const float* __restrict__ P, const int* __restrict__ x,
            const float* __restrict__ b3, float* __restrict__ e3,
            float* __restrict__ out)
{
    const int t = blockIdx.x, tid = threadIdx.x;
    __shared__ float sA[1536], sALA[1536], sSP[24], sLSP[24];
    __shared__ float bM[13 * kST], tbM[13 * kST], b3L[27 * kST], wred[32];
    for (int i = tid; i < 1536; i += 256) { sA[i] = P[oA + i]; sALA[i] = P[oALA + i]; }
    if (tid < 24) { sSP[tid] = P[oSP + tid]; sLSP[tid] = P[oLSP + tid]; }
    for (int u = tid; u < 27 * 64; u += 256) {
        int qq = u >> 6, idx = u & 63;
        b3L[qq * kST + idx] = b3[(t * 27 + qq) * 64 + idx];
    }
    __syncthreads();
    const float* pBm = P + oBm;
    const int xb = t * kNPT;

    // up: parents at global levels 2,1,0
    for (int f = 2; f >= 0; --f) {
        int pcnt = (f == 2) ? 9 : (f == 1 ? 3 : 1);
        int pl0  = (f == 2) ? 4 : (f == 1 ? 1 : 0);
        int cl0  = (f == 2) ? 13 : (f == 1 ? 4 : 1);
        for (int u = tid; u < pcnt * 8; u += 256) {
            int g = u & 7, pi = u >> 3;
            float acc[8];
            #pragma unroll
            for (int i = 0; i < 8; ++i) acc[i] = 0.f;
            #pragma unroll
            for (int k = 0; k < 3; ++k) {
                float bj[8];
                if (f == 2) {
                    int co = (3 * pi + k) * kST + g;
                    #pragma unroll
                    for (int j = 0; j < 8; ++j) bj[j] = b3L[co + j * 8];
                } else {
                    int co = (cl0 + 3 * pi + k) * kST + g;
                    #pragma unroll
                    for (int j = 0; j < 8; ++j) bj[j] = bM[co + j * 8];
                }
                float spg = sSP[k * 8 + g];
                #pragma unroll
                for (int i = 0; i < 8; ++i) {
                    float s = 0.f;
                    #pragma unroll
                    for (int j = 0; j < 8; ++j)
                        s += sA[((i * 8 + j) * 3 + k) * 8 + g] * bj[j];
                    acc[i] += spg * s;
                }
            }
            int ps = (pl0 + pi) * kST + g;
            #pragma unroll
            for (int i = 0; i < 8; ++i) tbM[ps + i * 8] = acc[i];
            int xv = x[xb + pl0 + pi];
            float s = 0.f;
            #pragma unroll
            for (int i = 0; i < 8; ++i) {
                acc[i] *= pBm[(i * 128 + xv) * 8 + g];
                s += acc[i];
            }
            float ig = __builtin_amdgcn_rcpf(s);
            #pragma unroll
            for (int i = 0; i < 8; ++i) bM[ps + i * 8] = acc[i] * ig;
        }
        __syncthreads();
    }

    float ell = 0.f;
    if (tid < 8) {                        // root Bm term (eps[root]=beta[root])
        int g = tid, xv = x[xb];
        #pragma unroll
        for (int c = 0; c < 8; ++c)
            ell += bM[c * 8 + g] * pBm[(c * 128 + xv) * 8 + g];
    }

    // down: children at global levels 1,2,3
    for (int f = 1; f <= 3; ++f) {
        int ccnt = (f == 1) ? 3 : (f == 2 ? 9 : 27);
        int cl0  = (f == 1) ? 1 : (f == 2 ? 4 : 13);
        int pl0  = (f == 1) ? 0 : (f == 2 ? 1 : 4);
        for (int u = tid; u < ccnt * 8; u += 256) {
            int g = u & 7, ci = u >> 3;
            int p = ci % 3;
            int ps = (pl0 + ci / 3) * kST + g;
            float r[8];
            #pragma unroll
            for (int i = 0; i < 8; ++i)
                r[i] = bM[ps + i * 8] * __builtin_amdgcn_rcpf(tbM[ps + i * 8]);
            float bj[8];
            if (f == 3) {
                int co = ci * kST + g;
                #pragma unroll
                for (int j = 0; j < 8; ++j) bj[j] = b3L[co + j * 8];
            } else {
                int co = (cl0 + ci) * kST + g;
                #pragma unroll
                for (int j = 0; j < 8; ++j) bj[j] = bM[co + j * 8];
            }
            float spg = sSP[p * 8 + g];
            float esum = 0.f, lg = 0.f;
            float ev[8];
            #pragma unroll
            for (int j = 0; j < 8; ++j) {
                float s1 = 0.f, s2 = 0.f;
                #pragma unroll
                for (int i = 0; i < 8; ++i) {
                    int ai = ((i * 8 + j) * 3 + p) * 8 + g;
                    s1 = fmaf(r[i], sA[ai],   s1);
                    s2 = fmaf(r[i], sALA[ai], s2);
                }
                float base = spg * bj[j];
                ev[j] = base * s1;
                lg   += base * s2;
                esum += ev[j];
            }
            lg += esum * sLSP[p * 8 + g];
            if (f == 3) {
                #pragma unroll
                for (int j = 0; j < 8; ++j)
                    e3[(t * 27 + ci) * 64 + j * 8 + g] = ev[j];
            } else {
                int co = (cl0 + ci) * kST + g;
                #pragma unroll
                for (int j = 0; j < 8; ++j) bM[co + j * 8] = ev[j];
            }
            int xv = x[xb + cl0 + ci];
            #pragma unroll
            for (int c = 0; c < 8; ++c)
                lg += ev[c] * pBm[(c * 128 + xv) * 8 + g];
            ell += lg;
        }
        __syncthreads();
    }

    ell += __shfl_xor(ell, 8);
    ell += __shfl_xor(ell, 16);
    ell += __shfl_xor(ell, 32);
    if ((tid & 63) < 8) wred[(tid >> 6) * 8 + (tid & 7)] = ell;
    __syncthreads();
    if (tid < 8) out[t * 8 + tid] = -(wred[tid] + wred[8 + tid] + wred[16 + tid] + wred[24 + tid]);
}

// ---------------- k3: subtree up replay + down-pass ----------------
__global__ __launch_bounds__(256)
void k3_down(const float* __restrict__ P, const int* __restrict__ x,
             const float* __restrict__ e3, float* __restrict__ out)
{
    const int blk = blockIdx.x, t = blk / 27, q = blk % 27, tid = threadIdx.x;
    __shared__ float sA[1536], sALA[1536], sPi[192], sLPi[192], sSP[24], sLSP[24];
    __shared__ float bL[121 * kST];   // beta -> r in place
    __shared__ float sSum[40 * 8];    // pre-norm sums, internal nodes (slot 0 unused)
    __shared__ float wred[32];
    for (int i = tid; i < 1536; i += 256) { sA[i] = P[oA + i]; sALA[i] = P[oALA + i]; }
    for (int i = tid; i < 192; i += 256)  { sPi[i] = P[oPi + i]; sLPi[i] = P[oLPi + i]; }
    if (tid < 24) { sSP[tid] = P[oSP + tid]; sLSP[tid] = P[oLSP + tid]; }
    __syncthreads();
    const float* pBm = P + oBm;
    const int xb = t * kNPT;

    // ---- up replay: leaves (slots 40..120) ----
    for (int u = tid; u < 81 * 8; u += 256) {
        int g = u & 7, li = u >> 3, p = li % 3;
        int xv = x[xb + 1093 + q * 81 + li];
        float v[8], s = 0.f;
        #pragma unroll
        for (int c = 0; c < 8; ++c) {
            v[c] = sPi[(c * 3 + p) * 8 + g] * pBm[(c * 128 + xv) * 8 + g];
            s += v[c];
        }
        float ig = __builtin_amdgcn_rcpf(s);
        int bo = (40 + li) * kST + g;
        #pragma unroll
        for (int c = 0; c < 8; ++c) bL[bo + c * 8] = v[c] * ig;
    }
    __syncthreads();

    // ---- up replay: internal; root (e==0) stores raw tb; others beta + s ----
    for (int e = 3; e >= 0; --e) {
        int pcnt = P3[e];
        for (int u = tid; u < pcnt * 8; u += 256) {
            int g = u & 7, pi = u >> 3;
            float acc[8];
            #pragma unroll
            for (int i = 0; i < 8; ++i) acc[i] = 0.f;
            #pragma unroll
            for (int k = 0; k < 3; ++k) {
                int co = (LO[e + 1] + 3 * pi + k) * kST + g;
                float bj[8];
                #pragma unroll
                for (int j = 0; j < 8; ++j) bj[j] = bL[co + j * 8];
                float spg = sSP[k * 8 + g];
                #pragma unroll
                for (int i = 0; i < 8; ++i) {
                    float s = 0.f;
                    #pragma unroll
                    for (int j = 0; j < 8; ++j)
                        s += sA[((i * 8 + j) * 3 + k) * 8 + g] * bj[j];
                    acc[i] += spg * s;
                }
            }
            if (e == 0) {
                #pragma unroll
                for (int i = 0; i < 8; ++i) bL[i * 8 + g] = acc[i];   // raw tb_root
            } else {
                int slot = LO[e] + pi;
                int xv = x[xb + GO[e] + q * pcnt + pi];
                float s = 0.f;
                #pragma unroll
                for (int i = 0; i < 8; ++i) {
                    acc[i] *= pBm[(i * 128 + xv) * 8 + g];
                    s += acc[i];
                }
                sSum[slot * 8 + g] = s;
                float ig = __builtin_amdgcn_rcpf(s);
                int bo = slot * kST + g;
                #pragma unroll
                for (int i = 0; i < 8; ++i) bL[bo + i * 8] = acc[i] * ig;
            }
        }
        __syncthreads();
    }

    // root r = eps(from k2) / tb_root, in place at slot 0
    if (tid < 64)
        bL[tid] = e3[(t * 27 + q) * 64 + tid] * __builtin_amdgcn_rcpf(bL[tid]);
    __syncthreads();

    // ---- down pass, local levels 1..4 (global 4..7) ----
    float ell = 0.f;
    for (int e = 1; e <= 4; ++e) {
        int ccnt = P3[e];
        int cl0 = LO[e], pl0 = LO[e - 1];
        for (int u = tid; u < ccnt * 8; u += 256) {
            int g = u & 7, ci = u >> 3;
            int p = ci % 3;
            int ps = (pl0 + ci / 3) * kST + g;
            float r[8];
            #pragma unroll
            for (int i = 0; i < 8; ++i) r[i] = bL[ps + i * 8];   // parent r
            int chSlot = cl0 + ci;
            int co = chSlot * kST + g;
            float bj[8];
            #pragma unroll
            for (int j = 0; j < 8; ++j) bj[j] = bL[co + j * 8];  // child beta
            float spg = sSP[p * 8 + g];
            float esum = 0.f, lg = 0.f;
            float ev[8];
            #pragma unroll
            for (int j = 0; j < 8; ++j) {
                float s1 = 0.f, s2 = 0.f;
                #pragma unroll
                for (int i = 0; i < 8; ++i) {
                    int ai = ((i * 8 + j) * 3 + p) * 8 + g;
                    s1 = fmaf(r[i], sA[ai],   s1);
                    s2 = fmaf(r[i], sALA[ai], s2);
                }
                float base = spg * bj[j];
                ev[j] = base * s1;
                lg   += base * s2;
                esum += ev[j];
            }
            lg += esum * sLSP[p * 8 + g];
            int xv = x[xb + GO[e] + q * ccnt + ci];
            float Bmv[8];
            #pragma unroll
            for (int c = 0; c < 8; ++c) {
                Bmv[c] = pBm[(c * 128 + xv) * 8 + g];
                lg += ev[c] * Bmv[c];
            }
            if (e < 4) {
                // child r = ev * Bm / (beta * s), in place
                float sv = sSum[chSlot * 8 + g];
                #pragma unroll
                for (int j = 0; j < 8; ++j)
                    bL[co + j * 8] = ev[j] * Bmv[j] * __builtin_amdgcn_rcpf(bj[j] * sv);
            } else {
                #pragma unroll
                for (int c = 0; c < 8; ++c)
                    lg += ev[c] * sLPi[(c * 3 + p) * 8 + g];
            }
            ell += lg;
        }
        __syncthreads();
    }

    ell += __shfl_xor(ell, 8);
    ell += __shfl_xor(ell, 16);
    ell += __shfl_xor(ell, 32);
    if ((tid & 63) < 8) wred[(tid >> 6) * 8 + (tid & 7)] = ell;
    __syncthreads();
    if (tid < 8)
        atomicAdd(&out[t * 8 + tid],
                  -(wred[tid] + wred[8 + tid] + wred[16 + tid] + wred[24 + tid]));
}

} // namespace

extern "C" void kernel_launch(void* const* d_in, const int* in_sizes, int n_in,
                              void* d_out, int out_size, void* d_ws, size_t ws_size,
                              hipStream_t stream) {
    const float* lamA  = (const float*)d_in[0];
    const float* lamB  = (const float*)d_in[1];
    const float* lamPi = (const float*)d_in[2];
    const float* lamSP = (const float*)d_in[3];
    const int*   x     = (const int*)d_in[4];
    float* out = (float*)d_out;
    float* P   = (float*)d_ws;          // oEnd floats
    float* b3  = P + oEnd;              // kB3 floats
    float* e3  = b3 + kB3;              // kB3 floats

    k0_params<<<dim3(1),    dim3(256), 0, stream>>>(lamA, lamB, lamPi, lamSP, P);
    k1_up    <<<dim3(1728), dim3(256), 0, stream>>>(P, x, b3);
    k2_mid   <<<dim3(64),   dim3(256), 0, stream>>>(P, x, b3, e3, out);
    k3_down  <<<dim3(1728), dim3(256), 0, stream>>>(P, x, e3, out);
}

// Round 5
// 166.952 us; speedup vs baseline: 3.3941x; 1.1208x over previous
//
#include <hip/hip_runtime.h>

// PosteriorHiddenTreeMarkovModel — MI355X / gfx950
// R5: wave-per-subtree. One 64-lane wave = one depth-4 subtree (8 nodes x 8 g
// lanes); 4 subtrees per 256-thread block. No __syncthreads in hot loops —
// wave-lockstep + in-order DS pipe; __builtin_amdgcn_wave_barrier() pins
// compiler ordering. k1/k3 grids = 432 blocks -> fully resident, no tail.
//  - leaves never stored: leaf beta recomputed on the fly (up & down)
//  - node stride 68 -> 2-way LDS conflicts (free) under 8-consecutive-node
//    wave access pattern
//  - per-subtree x staged in LDS; Bm transposed to [m][c][g] in k0
//  - k2: wave-per-tree (16 blocks), s-trick (no tb storage)

namespace {

constexpr int kNPT = 3280;
constexpr int kST  = 68;   // node record stride
__device__ __constant__ int LO[6] = {0, 1, 4, 13, 40, 121};
__device__ __constant__ int P3[5] = {1, 3, 9, 27, 81};

// ws param layout (floats)
constexpr int oA   = 0;      // 1536 softmax(A)     [i][j][p][g]
constexpr int oALA = 1536;   // 1536 A*log(A)
constexpr int oBm  = 3072;   // 8192 softmax(B|m)   TRANSPOSED: [m][c][g]
constexpr int oPi  = 11264;  // 192  softmax(Pi|c)  [c][p][g]
constexpr int oLPi = 11456;  // 192  log
constexpr int oSP  = 11648;  // 24   softmax(SP|p)  [p][g]
constexpr int oLSP = 11672;  // 24   log
constexpr int oEnd = 11712;
constexpr int kB3  = 64 * 27 * 64;

__device__ __forceinline__ void leaf_beta(const float* __restrict__ sPi,
                                          const float* __restrict__ pBm,
                                          int p, int xv, int g, float* b)
{
    float s = 0.f;
    #pragma unroll
    for (int c = 0; c < 8; ++c) {
        b[c] = sPi[(c * 3 + p) * 8 + g] * pBm[xv * 64 + c * 8 + g];
        s += b[c];
    }
    float ig = __builtin_amdgcn_rcpf(s);
    #pragma unroll
    for (int c = 0; c < 8; ++c) b[c] *= ig;
}

__global__ __launch_bounds__(256)
void k0_params(const float* __restrict__ lamA, const float* __restrict__ lamB,
               const float* __restrict__ lamPi, const float* __restrict__ lamSP,
               float* __restrict__ P)
{
    const int tid = threadIdx.x;
    __shared__ float rmax[256], rsum[256];

    for (int col = tid; col < 192; col += 256) {          // A over axis i (+ALA)
        int j = col / 24; int rem = col - j * 24; int p = rem >> 3; int g = rem & 7;
        float v[8]; float mx = -1e30f;
        #pragma unroll
        for (int i = 0; i < 8; ++i) {
            v[i] = lamA[((i * 8 + j) * 3 + p) * 8 + g];
            mx = fmaxf(mx, v[i]);
        }
        float s = 0.f;
        #pragma unroll
        for (int i = 0; i < 8; ++i) { v[i] = expf(v[i] - mx); s += v[i]; }
        float inv = 1.f / s;
        #pragma unroll
        for (int i = 0; i < 8; ++i) {
            int idx = ((i * 8 + j) * 3 + p) * 8 + g;
            float sm = v[i] * inv;
            P[oA + idx]   = sm;
            P[oALA + idx] = sm * logf(sm);
        }
    }
    {   // Bm softmax over m=128: 64 rows x 4 parts; write TRANSPOSED [m][c][g]
        int row = tid >> 2, part = tid & 3;
        int c = row >> 3, g = row & 7, m0 = part * 32;
        float mx = -1e30f;
        for (int mm = 0; mm < 32; ++mm)
            mx = fmaxf(mx, lamB[(c * 128 + m0 + mm) * 8 + g]);
        rmax[tid] = mx;
        __syncthreads();
        float m4 = fmaxf(fmaxf(rmax[row * 4], rmax[row * 4 + 1]),
                         fmaxf(rmax[row * 4 + 2], rmax[row * 4 + 3]));
        float s = 0.f;
        for (int mm = 0; mm < 32; ++mm)
            s += expf(lamB[(c * 128 + m0 + mm) * 8 + g] - m4);
        rsum[tid] = s;
        __syncthreads();
        float stot = rsum[row * 4] + rsum[row * 4 + 1] + rsum[row * 4 + 2] + rsum[row * 4 + 3];
        float inv = 1.f / stot;
        for (int mm = 0; mm < 32; ++mm) {
            P[oBm + (m0 + mm) * 64 + c * 8 + g] =
                expf(lamB[(c * 128 + m0 + mm) * 8 + g] - m4) * inv;
        }
    }
    for (int col = tid; col < 24; col += 256) {           // Pi over axis c
        int p = col >> 3; int g = col & 7;
        float v[8]; float mx = -1e30f;
        #pragma unroll
        for (int c = 0; c < 8; ++c) {
            v[c] = lamPi[(c * 3 + p) * 8 + g];
            mx = fmaxf(mx, v[c]);
        }
        float s = 0.f;
        #pragma unroll
        for (int c = 0; c < 8; ++c) { v[c] = expf(v[c] - mx); s += v[c]; }
        float inv = 1.f / s;
        #pragma unroll
        for (int c = 0; c < 8; ++c) {
            int idx = (c * 3 + p) * 8 + g;
            float sm = v[c] * inv;
            P[oPi + idx]  = sm;
            P[oLPi + idx] = logf(sm);
        }
    }
    if (tid < 8) {                                        // SP over axis p
        int g = tid;
        float v0 = lamSP[g], v1 = lamSP[8 + g], v2 = lamSP[16 + g];
        float mx = fmaxf(v0, fmaxf(v1, v2));
        float e0 = expf(v0 - mx), e1 = expf(v1 - mx), e2 = expf(v2 - mx);
        float inv = 1.f / (e0 + e1 + e2);
        P[oSP + g]       = e0 * inv; P[oSP + 8 + g]  = e1 * inv; P[oSP + 16 + g] = e2 * inv;
        P[oLSP + g]      = logf(e0 * inv);
        P[oLSP + 8 + g]  = logf(e1 * inv);
        P[oLSP + 16 + g] = logf(e2 * inv);
    }
}

// ---------------- k1: subtree up-pass (wave-per-subtree), emit root beta -----
__global__ __launch_bounds__(256)
void k1_up(const float* __restrict__ P, const int* __restrict__ x,
           float* __restrict__ b3)
{
    const int tid = threadIdx.x, w = tid >> 6, lane = tid & 63;
    const int n = lane >> 3, g = lane & 7;
    __shared__ float sA[1536], sPi[192], sSP[24];
    __shared__ float bW[4][40 * kST];
    __shared__ int   xW[4][124];
    for (int i = tid; i < 1536; i += 256) sA[i] = P[oA + i];
    for (int i = tid; i < 192; i += 256)  sPi[i] = P[oPi + i];
    if (tid < 24) sSP[tid] = P[oSP + tid];
    __syncthreads();
    const float* pBm = P + oBm;
    const int id = blockIdx.x * 4 + w, t = id / 27, q = id % 27, xb = t * kNPT;
    float* bw = bW[w]; int* xw = xW[w];

    for (int u = lane; u < 121; u += 64) {
        int gx;
        if (u == 0)       gx = 13 + q;
        else if (u < 4)   gx = 40  + q * 3  + (u - 1);
        else if (u < 13)  gx = 121 + q * 9  + (u - 4);
        else if (u < 40)  gx = 364 + q * 27 + (u - 13);
        else              gx = 1093 + q * 81 + (u - 40);
        xw[u] = x[xb + gx];
    }
    __builtin_amdgcn_wave_barrier();

    for (int e = 3; e >= 0; --e) {
        int cnt = P3[e];
        for (int base = 0; base < cnt; base += 8) {
            int pi = base + n;
            if (pi < cnt) {
                float acc[8];
                #pragma unroll
                for (int i = 0; i < 8; ++i) acc[i] = 0.f;
                #pragma unroll
                for (int k = 0; k < 3; ++k) {
                    float bj[8];
                    if (e == 3) {
                        leaf_beta(sPi, pBm, k, xw[40 + 3 * pi + k], g, bj);
                    } else {
                        int co = (LO[e + 1] + 3 * pi + k) * kST + g;
                        #pragma unroll
                        for (int j = 0; j < 8; ++j) bj[j] = bw[co + j * 8];
                    }
                    float spg = sSP[k * 8 + g];
                    #pragma unroll
                    for (int i = 0; i < 8; ++i) {
                        float s = 0.f;
                        #pragma unroll
                        for (int j = 0; j < 8; ++j)
                            s = fmaf(sA[((i * 8 + j) * 3 + k) * 8 + g], bj[j], s);
                        acc[i] = fmaf(spg, s, acc[i]);
                    }
                }
                int xv = xw[LO[e] + pi];
                float s = 0.f;
                #pragma unroll
                for (int i = 0; i < 8; ++i) { acc[i] *= pBm[xv * 64 + i * 8 + g]; s += acc[i]; }
                float ig = __builtin_amdgcn_rcpf(s);
                if (e == 0) {
                    #pragma unroll
                    for (int i = 0; i < 8; ++i) b3[id * 64 + i * 8 + g] = acc[i] * ig;
                } else {
                    int bo = (LO[e] + pi) * kST + g;
                    #pragma unroll
                    for (int i = 0; i < 8; ++i) bw[bo + i * 8] = acc[i] * ig;
                }
            }
        }
        __builtin_amdgcn_wave_barrier();
    }
}

// ---------------- k2: levels 0-3 up+down (wave-per-tree, 16 blocks) ----------
__global__ __launch_bounds__(256)
void k2_mid(const float* __restrict__ P, const int* __restrict__ x,
            const float* __restrict__ b3, float* __restrict__ e3,
            float* __restrict__ out)
{
    const int tid = threadIdx.x, w = tid >> 6, lane = tid & 63;
    const int n = lane >> 3, g = lane & 7;
    __shared__ float sA[1536], sALA[1536], sSP[24], sLSP[24];
    __shared__ float b3W[4][27 * kST], bMW[4][13 * kST], sSW[4][13 * 8];
    __shared__ int   xW[4][40];
    for (int i = tid; i < 1536; i += 256) { sA[i] = P[oA + i]; sALA[i] = P[oALA + i]; }
    if (tid < 24) { sSP[tid] = P[oSP + tid]; sLSP[tid] = P[oLSP + tid]; }
    __syncthreads();
    const float* pBm = P + oBm;
    const int t = blockIdx.x * 4 + w, xb = t * kNPT;
    float* b3w = b3W[w]; float* bM = bMW[w]; float* sw = sSW[w]; int* xw = xW[w];

    for (int u = lane; u < 27 * 64; u += 64) {
        int slot = u >> 6, idx = u & 63;
        b3w[slot * kST + idx] = b3[(t * 27 + slot) * 64 + idx];
    }
    for (int u = lane; u < 40; u += 64) xw[u] = x[xb + u];
    __builtin_amdgcn_wave_barrier();

    // up: parents at global levels 2,1,0 (store beta + s)
    for (int f = 2; f >= 0; --f) {
        int cnt = (f == 2) ? 9 : (f == 1 ? 3 : 1);
        int pl0 = (f == 2) ? 4 : (f == 1 ? 1 : 0);
        int cl0 = (f == 1) ? 4 : 1;   // bM child base for f<2
        for (int base = 0; base < cnt; base += 8) {
            int pi = base + n;
            if (pi < cnt) {
                float acc[8];
                #pragma unroll
                for (int i = 0; i < 8; ++i) acc[i] = 0.f;
                #pragma unroll
                for (int k = 0; k < 3; ++k) {
                    float bj[8];
                    if (f == 2) {
                        int co = (3 * pi + k) * kST + g;
                        #pragma unroll
                        for (int j = 0; j < 8; ++j) bj[j] = b3w[co + j * 8];
                    } else {
                        int co = (cl0 + 3 * pi + k) * kST + g;
                        #pragma unroll
                        for (int j = 0; j < 8; ++j) bj[j] = bM[co + j * 8];
                    }
                    float spg = sSP[k * 8 + g];
                    #pragma unroll
                    for (int i = 0; i < 8; ++i) {
                        float s = 0.f;
                        #pragma unroll
                        for (int j = 0; j < 8; ++j)
                            s = fmaf(sA[((i * 8 + j) * 3 + k) * 8 + g], bj[j], s);
                        acc[i] = fmaf(spg, s, acc[i]);
                    }
                }
                int slot = pl0 + pi;
                int xv = xw[slot];
                float s = 0.f;
                #pragma unroll
                for (int i = 0; i < 8; ++i) { acc[i] *= pBm[xv * 64 + i * 8 + g]; s += acc[i]; }
                sw[slot * 8 + g] = s;
                float ig = __builtin_amdgcn_rcpf(s);
                int bo = slot * kST + g;
                #pragma unroll
                for (int i = 0; i < 8; ++i) bM[bo + i * 8] = acc[i] * ig;
            }
        }
        __builtin_amdgcn_wave_barrier();
    }

    float ell = 0.f;
    if (n == 0) {        // root Bm term, then overwrite slot0 with r = Bm/s
        int xv = xw[0];
        float invs = __builtin_amdgcn_rcpf(sw[g]);
        #pragma unroll
        for (int c = 0; c < 8; ++c)
            ell += bM[c * 8 + g] * pBm[xv * 64 + c * 8 + g];
        #pragma unroll
        for (int c = 0; c < 8; ++c)
            bM[c * 8 + g] = pBm[xv * 64 + c * 8 + g] * invs;
    }
    __builtin_amdgcn_wave_barrier();

    // down: children at global levels 1,2,3
    for (int f = 1; f <= 3; ++f) {
        int cnt = (f == 1) ? 3 : (f == 2 ? 9 : 27);
        int cl0 = (f == 1) ? 1 : (f == 2 ? 4 : 13);
        int pl0 = (f == 1) ? 0 : (f == 2 ? 1 : 4);
        for (int base = 0; base < cnt; base += 8) {
            int ci = base + n;
            if (ci < cnt) {
                int p = ci % 3;
                int ps = (pl0 + ci / 3) * kST + g;
                float r[8];
                #pragma unroll
                for (int i = 0; i < 8; ++i) r[i] = bM[ps + i * 8];
                float bj[8];
                if (f == 3) {
                    int co = ci * kST + g;
                    #pragma unroll
                    for (int j = 0; j < 8; ++j) bj[j] = b3w[co + j * 8];
                } else {
                    int co = (cl0 + ci) * kST + g;
                    #pragma unroll
                    for (int j = 0; j < 8; ++j) bj[j] = bM[co + j * 8];
                }
                float spg = sSP[p * 8 + g];
                float esum = 0.f, lg = 0.f;
                float ev[8];
                #pragma unroll
                for (int j = 0; j < 8; ++j) {
                    float s1 = 0.f, s2 = 0.f;
                    #pragma unroll
                    for (int i = 0; i < 8; ++i) {
                        int ai = ((i * 8 + j) * 3 + p) * 8 + g;
                        s1 = fmaf(r[i], sA[ai],   s1);
                        s2 = fmaf(r[i], sALA[ai], s2);
                    }
                    float bs = spg * bj[j];
                    ev[j] = bs * s1;
                    lg    = fmaf(bs, s2, lg);
                    esum += ev[j];
                }
                lg = fmaf(esum, sLSP[p * 8 + g], lg);
                int xv = xw[cl0 + ci];
                float Bmv[8];
                #pragma unroll
                for (int c = 0; c < 8; ++c) {
                    Bmv[c] = pBm[xv * 64 + c * 8 + g];
                    lg = fmaf(ev[c], Bmv[c], lg);
                }
                if (f == 3) {
                    #pragma unroll
                    for (int j = 0; j < 8; ++j)
                        e3[(t * 27 + ci) * 64 + j * 8 + g] = ev[j];
                } else {
                    float sv = sw[(cl0 + ci) * 8 + g];
                    int co = (cl0 + ci) * kST + g;
                    #pragma unroll
                    for (int j = 0; j < 8; ++j)
                        bM[co + j * 8] = ev[j] * Bmv[j] * __builtin_amdgcn_rcpf(bj[j] * sv);
                }
                ell += lg;
            }
        }
        __builtin_amdgcn_wave_barrier();
    }

    ell += __shfl_xor(ell, 8);
    ell += __shfl_xor(ell, 16);
    ell += __shfl_xor(ell, 32);
    if (n == 0) out[t * 8 + g] = -ell;
}

// ---------------- k3: subtree up replay + down (wave-per-subtree) ------------
__global__ __launch_bounds__(256)
void k3_down(const float* __restrict__ P, const int* __restrict__ x,
             const float* __restrict__ e3, float* __restrict__ out)
{
    const int tid = threadIdx.x, w = tid >> 6, lane = tid & 63;
    const int n = lane >> 3, g = lane & 7;
    __shared__ float sA[1536], sALA[1536], sPi[192], sLPi[192], sSP[24], sLSP[24];
    __shared__ float bW[4][40 * kST];
    __shared__ float sSW[4][40 * 8];
    __shared__ int   xW[4][124];
    for (int i = tid; i < 1536; i += 256) { sA[i] = P[oA + i]; sALA[i] = P[oALA + i]; }
    for (int i = tid; i < 192; i += 256)  { sPi[i] = P[oPi + i]; sLPi[i] = P[oLPi + i]; }
    if (tid < 24) { sSP[tid] = P[oSP + tid]; sLSP[tid] = P[oLSP + tid]; }
    __syncthreads();
    const float* pBm = P + oBm;
    const int id = blockIdx.x * 4 + w, t = id / 27, q = id % 27, xb = t * kNPT;
    float* bw = bW[w]; float* sw = sSW[w]; int* xw = xW[w];

    for (int u = lane; u < 121; u += 64) {
        int gx;
        if (u == 0)       gx = 13 + q;
        else if (u < 4)   gx = 40  + q * 3  + (u - 1);
        else if (u < 13)  gx = 121 + q * 9  + (u - 4);
        else if (u < 40)  gx = 364 + q * 27 + (u - 13);
        else              gx = 1093 + q * 81 + (u - 40);
        xw[u] = x[xb + gx];
    }
    __builtin_amdgcn_wave_barrier();

    // up replay: e=3..1 store beta+s; e=0 stores raw tb into slot 0
    for (int e = 3; e >= 0; --e) {
        int cnt = P3[e];
        for (int base = 0; base < cnt; base += 8) {
            int pi = base + n;
            if (pi < cnt) {
                float acc[8];
                #pragma unroll
                for (int i = 0; i < 8; ++i) acc[i] = 0.f;
                #pragma unroll
                for (int k = 0; k < 3; ++k) {
                    float bj[8];
                    if (e == 3) {
                        leaf_beta(sPi, pBm, k, xw[40 + 3 * pi + k], g, bj);
                    } else {
                        int co = (LO[e + 1] + 3 * pi + k) * kST + g;
                        #pragma unroll
                        for (int j = 0; j < 8; ++j) bj[j] = bw[co + j * 8];
                    }
                    float spg = sSP[k * 8 + g];
                    #pragma unroll
                    for (int i = 0; i < 8; ++i) {
                        float s = 0.f;
                        #pragma unroll
                        for (int j = 0; j < 8; ++j)
                            s = fmaf(sA[((i * 8 + j) * 3 + k) * 8 + g], bj[j], s);
                        acc[i] = fmaf(spg, s, acc[i]);
                    }
                }
                if (e == 0) {
                    #pragma unroll
                    for (int i = 0; i < 8; ++i) bw[i * 8 + g] = acc[i];   // raw tb
                } else {
                    int slot = LO[e] + pi;
                    int xv = xw[slot];
                    float s = 0.f;
                    #pragma unroll
                    for (int i = 0; i < 8; ++i) { acc[i] *= pBm[xv * 64 + i * 8 + g]; s += acc[i]; }
                    sw[slot * 8 + g] = s;
                    float ig = __builtin_amdgcn_rcpf(s);
                    int bo = slot * kST + g;
                    #pragma unroll
                    for (int i = 0; i < 8; ++i) bw[bo + i * 8] = acc[i] * ig;
                }
            }
        }
        __builtin_amdgcn_wave_barrier();
    }

    // root r = eps(from k2) / tb_root, in place (slot 0)
    bw[lane] = e3[id * 64 + lane] * __builtin_amdgcn_rcpf(bw[lane]);
    __builtin_amdgcn_wave_barrier();

    // down: local levels 1..4 (global 4..7); parent slots hold r
    float ell = 0.f;
    for (int e = 1; e <= 4; ++e) {
        int cnt = P3[e], pl0 = LO[e - 1];
        for (int base = 0; base < cnt; base += 8) {
            int ci = base + n;
            if (ci < cnt) {
                int p = ci % 3;
                int ps = (pl0 + ci / 3) * kST + g;
                float r[8];
                #pragma unroll
                for (int i = 0; i < 8; ++i) r[i] = bw[ps + i * 8];
                float bj[8];
                int xv;
                if (e == 4) {
                    xv = xw[40 + ci];
                    leaf_beta(sPi, pBm, p, xv, g, bj);
                } else {
                    int slot = LO[e] + ci;
                    xv = xw[slot];
                    int co = slot * kST + g;
                    #pragma unroll
                    for (int j = 0; j < 8; ++j) bj[j] = bw[co + j * 8];
                }
                float spg = sSP[p * 8 + g];
                float esum = 0.f, lg = 0.f;
                float ev[8];
                #pragma unroll
                for (int j = 0; j < 8; ++j) {
                    float s1 = 0.f, s2 = 0.f;
                    #pragma unroll
                    for (int i = 0; i < 8; ++i) {
                        int ai = ((i * 8 + j) * 3 + p) * 8 + g;
                        s1 = fmaf(r[i], sA[ai],   s1);
                        s2 = fmaf(r[i], sALA[ai], s2);
                    }
                    float bs = spg * bj[j];
                    ev[j] = bs * s1;
                    lg    = fmaf(bs, s2, lg);
                    esum += ev[j];
                }
                lg = fmaf(esum, sLSP[p * 8 + g], lg);
                float Bmv[8];
                #pragma unroll
                for (int c = 0; c < 8; ++c) {
                    Bmv[c] = pBm[xv * 64 + c * 8 + g];
                    lg = fmaf(ev[c], Bmv[c], lg);
                }
                if (e < 4) {
                    int slot = LO[e] + ci;
                    float sv = sw[slot * 8 + g];
                    int co = slot * kST + g;
                    #pragma unroll
                    for (int j = 0; j < 8; ++j)
                        bw[co + j * 8] = ev[j] * Bmv[j] * __builtin_amdgcn_rcpf(bj[j] * sv);
                } else {
                    #pragma unroll
                    for (int c = 0; c < 8; ++c)
                        lg = fmaf(ev[c], sLPi[(c * 3 + p) * 8 + g], lg);
                }
                ell += lg;
            }
        }
        __builtin_amdgcn_wave_barrier();
    }

    ell += __shfl_xor(ell, 8);
    ell += __shfl_xor(ell, 16);
    ell += __shfl_xor(ell, 32);
    if (n == 0) atomicAdd(&out[t * 8 + g], -ell);
}

} // namespace

extern "C" void kernel_launch(void* const* d_in, const int* in_sizes, int n_in,
                              void* d_out, int out_size, void* d_ws, size_t ws_size,
                              hipStream_t stream) {
    const float* lamA  = (const float*)d_in[0];
    const float* lamB  = (const float*)d_in[1];
    const float* lamPi = (const float*)d_in[2];
    const float* lamSP = (const float*)d_in[3];
    const int*   x     = (const int*)d_in[4];
    float* out = (float*)d_out;
    float* P   = (float*)d_ws;          // oEnd floats
    float* b3  = P + oEnd;              // kB3 floats
    float* e3  = b3 + kB3;              // kB3 floats

    k0_params<<<dim3(1),   dim3(256), 0, stream>>>(lamA, lamB, lamPi, lamSP, P);
    k1_up    <<<dim3(432), dim3(256), 0, stream>>>(P, x, b3);
    k2_mid   <<<dim3(16),  dim3(256), 0, stream>>>(P, x, b3, e3, out);
    k3_down  <<<dim3(432), dim3(256), 0, stream>>>(P, x, e3, out);
}